// Round 3
// baseline (190.033 us; speedup 1.0000x reference)
//
#include <hip/hip_runtime.h>
#include <math.h>

#define GRID 4096   // blocks; 4 waves/block -> 16384 waves = 16384 rows

__device__ inline float nsq(float s2) {
    // sum(normalize(x)^2) = s2 / max(sqrt(s2), eps)^2  (F.normalize semantics)
    const float eps = 1e-12f;
    float m = fmaxf(sqrtf(s2), eps);
    return s2 / (m * m);
}

// Fused: per-row sum-of-squares (one wave per row) + last-block finalize.
__global__ __launch_bounds__(256) void fused_kernel(
    const float* __restrict__ m0, const float* __restrict__ m1,
    const float* __restrict__ m2, const float* __restrict__ m3,
    float* __restrict__ row_ss /* [16384] */,
    unsigned int* __restrict__ counter,
    float* __restrict__ out) {
    const int wid  = (blockIdx.x << 2) | (threadIdx.x >> 6);  // flat row id
    const int lane = threadIdx.x & 63;
    const int mat  = wid >> 12;
    const int row  = wid & 4095;
    const float* in = (mat == 0) ? m0 : (mat == 1) ? m1 : (mat == 2) ? m2 : m3;

    const float4* p = reinterpret_cast<const float4*>(in + (size_t)row * 4096);

    float acc = 0.0f;
#pragma unroll
    for (int half = 0; half < 2; ++half) {
        float4 v[8];
#pragma unroll
        for (int k = 0; k < 8; ++k) v[k] = p[lane + (half << 9) + (k << 6)];
        // Pin: issue all 8 global_load_dwordx4 before any FMA consumes them.
        __builtin_amdgcn_sched_barrier(0);
#pragma unroll
        for (int k = 0; k < 8; ++k) {
            acc = fmaf(v[k].x, v[k].x, acc);
            acc = fmaf(v[k].y, v[k].y, acc);
            acc = fmaf(v[k].z, v[k].z, acc);
            acc = fmaf(v[k].w, v[k].w, acc);
        }
    }

#pragma unroll
    for (int off = 32; off > 0; off >>= 1) acc += __shfl_down(acc, off);
    if (lane == 0) row_ss[wid] = acc;

    // ---- last-block-done finalize (device-scope, G12/G16) ----
    __syncthreads();                 // all 4 rows of this block written
    __shared__ bool is_last;
    if (threadIdx.x == 0) {
        __threadfence();             // release: row_ss visible device-wide
        unsigned int old = atomicAdd(counter, 1u);
        is_last = (old == GRID - 1);
    }
    __syncthreads();
    if (!is_last) return;

    __threadfence();                 // acquire: see all blocks' row_ss
    const float* r2  = row_ss;           // uni_repr_rna
    const float* w2  = row_ss + 4096;    // uni_repr_wsi
    const float* rw2 = row_ss + 8192;    // uni_repr_rna_wsi
    const float* wr2 = row_ss + 12288;   // uni_repr_wsi_rna

    float sum_d1 = 0.0f, sum_d2 = 0.0f;
    for (int i = threadIdx.x; i < 4096; i += 256) {
        float a = r2[i], b = w2[i], c = rw2[i], d = wr2[i];
        sum_d1 += nsq(a) * nsq(b);            // D1
        sum_d2 += nsq(d + c) * nsq(a + b);    // D2 (concat norms add)
    }
#pragma unroll
    for (int off = 32; off > 0; off >>= 1) {
        sum_d1 += __shfl_down(sum_d1, off);
        sum_d2 += __shfl_down(sum_d2, off);
    }
    __shared__ float s1[4], s2[4];
    if ((threadIdx.x & 63) == 0) {
        s1[threadIdx.x >> 6] = sum_d1;
        s2[threadIdx.x >> 6] = sum_d2;
    }
    __syncthreads();
    if (threadIdx.x == 0) {
        float d1 = ((s1[0] + s1[1]) + (s1[2] + s1[3])) * (1.0f / 4096.0f);
        float d2 = ((s2[0] + s2[1]) + (s2[2] + s2[3])) * (1.0f / 4096.0f);
        out[0] = 0.5f * d2 + 0.5f * d1;  // loss
        out[1] = d1;                     // loss_D1
        out[2] = d2;                     // loss_D2
    }
}

extern "C" void kernel_launch(void* const* d_in, const int* in_sizes, int n_in,
                              void* d_out, int out_size, void* d_ws, size_t ws_size,
                              hipStream_t stream) {
    const float* rna    = (const float*)d_in[0];
    const float* wsi    = (const float*)d_in[1];
    const float* rnawsi = (const float*)d_in[2];
    const float* wsirna = (const float*)d_in[3];
    float* out = (float*)d_out;
    float* row_ss = (float*)d_ws;                       // 16384 floats = 64 KB
    unsigned int* counter = (unsigned int*)((char*)d_ws + 16384 * sizeof(float));

    hipMemsetAsync(counter, 0, sizeof(unsigned int), stream);  // graph-capture legal
    fused_kernel<<<GRID, 256, 0, stream>>>(rna, wsi, rnawsi, wsirna, row_ss, counter, out);
}

// Round 4
// 52.322 us; speedup vs baseline: 3.6320x; 3.6320x over previous
//
#include <hip/hip_runtime.h>
#include <math.h>

typedef float fx4 __attribute__((ext_vector_type(4)));

// Per-row sum of squares. One block (256 threads) per (matrix, row).
// grid = 4 * 4096 blocks. Each row = 4096 f32 = 1024 fx4; 4 fx4/thread, coalesced.
//
// L3 residency engineering: total input = 4 x 64 MiB = 256 MiB = exactly L3
// capacity, so plain streaming thrashes at ~50% hit. Rows with (row&7)==7
// (1/8 of the data, 32 MiB) are loaded non-temporally (no cache allocation),
// leaving 224 MiB to stay L3-resident across timed replays.
__global__ __launch_bounds__(256) void rowsumsq_kernel(
    const float* __restrict__ m0, const float* __restrict__ m1,
    const float* __restrict__ m2, const float* __restrict__ m3,
    float* __restrict__ row_ss /* [4*4096] */) {
    const int bid = blockIdx.x;
    const int mat = bid >> 12;
    const int row = bid & 4095;
    const float* in = (mat == 0) ? m0 : (mat == 1) ? m1 : (mat == 2) ? m2 : m3;

    const fx4* p = reinterpret_cast<const fx4*>(in + (size_t)row * 4096);
    const int t = threadIdx.x;

    fx4 v0, v1, v2, v3;
    if ((row & 7) == 7) {  // wave-uniform branch: streaming slice, bypass cache
        v0 = __builtin_nontemporal_load(p + t);
        v1 = __builtin_nontemporal_load(p + t + 256);
        v2 = __builtin_nontemporal_load(p + t + 512);
        v3 = __builtin_nontemporal_load(p + t + 768);
    } else {               // resident slice: normal cached loads
        v0 = p[t];
        v1 = p[t + 256];
        v2 = p[t + 512];
        v3 = p[t + 768];
    }

    // 4 independent accumulator chains (ILP without sched_barrier pinning)
    float a0 = v0.x * v0.x + v0.y * v0.y + v0.z * v0.z + v0.w * v0.w;
    float a1 = v1.x * v1.x + v1.y * v1.y + v1.z * v1.z + v1.w * v1.w;
    float a2 = v2.x * v2.x + v2.y * v2.y + v2.z * v2.z + v2.w * v2.w;
    float a3 = v3.x * v3.x + v3.y * v3.y + v3.z * v3.z + v3.w * v3.w;
    float acc = (a0 + a1) + (a2 + a3);

    // wave64 reduce
#pragma unroll
    for (int off = 32; off > 0; off >>= 1) acc += __shfl_down(acc, off);

    __shared__ float s[4];
    if ((threadIdx.x & 63) == 0) s[threadIdx.x >> 6] = acc;
    __syncthreads();
    if (threadIdx.x == 0) row_ss[bid] = (s[0] + s[1]) + (s[2] + s[3]);
}

__device__ inline float nsq(float s2) {
    // sum(normalize(x)^2) = s2 / max(sqrt(s2), eps)^2  (F.normalize semantics)
    const float eps = 1e-12f;
    float m = fmaxf(sqrtf(s2), eps);
    return s2 / (m * m);
}

// Single block: combine 4*4096 row sums into the 3 scalars.
__global__ __launch_bounds__(256) void finalize_kernel(
    const float* __restrict__ row_ss, float* __restrict__ out) {
    const float* r2  = row_ss;              // uni_repr_rna
    const float* w2  = row_ss + 4096;       // uni_repr_wsi
    const float* rw2 = row_ss + 8192;       // uni_repr_rna_wsi
    const float* wr2 = row_ss + 12288;      // uni_repr_wsi_rna

    float sum_d1 = 0.0f, sum_d2 = 0.0f;
    for (int i = threadIdx.x; i < 4096; i += 256) {
        float a = r2[i], b = w2[i], c = rw2[i], d = wr2[i];
        sum_d1 += nsq(a) * nsq(b);            // D1
        sum_d2 += nsq(d + c) * nsq(a + b);    // D2 (concat norms add)
    }

#pragma unroll
    for (int off = 32; off > 0; off >>= 1) {
        sum_d1 += __shfl_down(sum_d1, off);
        sum_d2 += __shfl_down(sum_d2, off);
    }
    __shared__ float s1[4], s2[4];
    if ((threadIdx.x & 63) == 0) {
        s1[threadIdx.x >> 6] = sum_d1;
        s2[threadIdx.x >> 6] = sum_d2;
    }
    __syncthreads();
    if (threadIdx.x == 0) {
        float d1 = ((s1[0] + s1[1]) + (s1[2] + s1[3])) * (1.0f / 4096.0f);
        float d2 = ((s2[0] + s2[1]) + (s2[2] + s2[3])) * (1.0f / 4096.0f);
        out[0] = 0.5f * d2 + 0.5f * d1;  // loss
        out[1] = d1;                     // loss_D1
        out[2] = d2;                     // loss_D2
    }
}

extern "C" void kernel_launch(void* const* d_in, const int* in_sizes, int n_in,
                              void* d_out, int out_size, void* d_ws, size_t ws_size,
                              hipStream_t stream) {
    const float* rna    = (const float*)d_in[0];
    const float* wsi    = (const float*)d_in[1];
    const float* rnawsi = (const float*)d_in[2];
    const float* wsirna = (const float*)d_in[3];
    float* out = (float*)d_out;
    float* row_ss = (float*)d_ws;  // 4*4096 floats = 64 KB

    rowsumsq_kernel<<<4 * 4096, 256, 0, stream>>>(rna, wsi, rnawsi, wsirna, row_ss);
    finalize_kernel<<<1, 256, 0, stream>>>(row_ss, out);
}

// Round 5
// 47.986 us; speedup vs baseline: 3.9602x; 1.0903x over previous
//
#include <hip/hip_runtime.h>
#include <math.h>

typedef float fx4 __attribute__((ext_vector_type(4)));

// Persistent, m13-copy-shaped: 2048 blocks x 256 threads = 8192 waves,
// each wave owns 2 contiguous rows (32 KB contiguous stream, 32 float4/lane).
// Long-lived waves keep loads in flight across the per-row reduce tails
// (compiler can hoist row r+1 loads above row r's shuffle chain).
// No LDS, no __syncthreads in the hot kernel.
__global__ __launch_bounds__(256) void rowsumsq_kernel(
    const float* __restrict__ m0, const float* __restrict__ m1,
    const float* __restrict__ m2, const float* __restrict__ m3,
    float* __restrict__ row_ss /* [16384] */) {
    const int wid  = (blockIdx.x << 2) | (threadIdx.x >> 6);  // 0..8191
    const int lane = threadIdx.x & 63;
    const int r0   = wid << 1;          // first flat row; both rows same matrix
    const int mat  = r0 >> 12;
    const int row  = r0 & 4095;
    const float* in = (mat == 0) ? m0 : (mat == 1) ? m1 : (mat == 2) ? m2 : m3;

    const fx4* p = reinterpret_cast<const fx4*>(in + (size_t)row * 4096) + lane;

#pragma unroll
    for (int rr = 0; rr < 2; ++rr) {
        const fx4* q = p + rr * 1024;
        // 16 loads, 4 independent accumulator chains.
        float c0 = 0.f, c1 = 0.f, c2 = 0.f, c3 = 0.f;
#pragma unroll
        for (int k = 0; k < 4; ++k) {
            fx4 v0 = q[(k * 4 + 0) * 64];
            fx4 v1 = q[(k * 4 + 1) * 64];
            fx4 v2 = q[(k * 4 + 2) * 64];
            fx4 v3 = q[(k * 4 + 3) * 64];
            c0 += v0.x * v0.x + v0.y * v0.y + v0.z * v0.z + v0.w * v0.w;
            c1 += v1.x * v1.x + v1.y * v1.y + v1.z * v1.z + v1.w * v1.w;
            c2 += v2.x * v2.x + v2.y * v2.y + v2.z * v2.z + v2.w * v2.w;
            c3 += v3.x * v3.x + v3.y * v3.y + v3.z * v3.z + v3.w * v3.w;
        }
        float acc = (c0 + c1) + (c2 + c3);
#pragma unroll
        for (int off = 32; off > 0; off >>= 1) acc += __shfl_down(acc, off);
        if (lane == 0) row_ss[r0 + rr] = acc;
    }
}

__device__ inline float nsq(float s2) {
    // sum(normalize(x)^2) = s2 / max(sqrt(s2), eps)^2  (F.normalize semantics)
    const float eps = 1e-12f;
    float m = fmaxf(sqrtf(s2), eps);
    return s2 / (m * m);
}

// Single block: combine 4*4096 row sums into the 3 scalars. float4-vectorized.
__global__ __launch_bounds__(256) void finalize_kernel(
    const float* __restrict__ row_ss, float* __restrict__ out) {
    const fx4* r2  = reinterpret_cast<const fx4*>(row_ss);          // rna
    const fx4* w2  = reinterpret_cast<const fx4*>(row_ss + 4096);   // wsi
    const fx4* rw2 = reinterpret_cast<const fx4*>(row_ss + 8192);   // rna_wsi
    const fx4* wr2 = reinterpret_cast<const fx4*>(row_ss + 12288);  // wsi_rna

    float sum_d1 = 0.0f, sum_d2 = 0.0f;
    for (int i = threadIdx.x; i < 1024; i += 256) {
        fx4 a = r2[i], b = w2[i], c = rw2[i], d = wr2[i];
#pragma unroll
        for (int j = 0; j < 4; ++j) {
            sum_d1 += nsq(a[j]) * nsq(b[j]);            // D1
            sum_d2 += nsq(d[j] + c[j]) * nsq(a[j] + b[j]);  // D2 (concat norms add)
        }
    }

#pragma unroll
    for (int off = 32; off > 0; off >>= 1) {
        sum_d1 += __shfl_down(sum_d1, off);
        sum_d2 += __shfl_down(sum_d2, off);
    }
    __shared__ float s1[4], s2[4];
    if ((threadIdx.x & 63) == 0) {
        s1[threadIdx.x >> 6] = sum_d1;
        s2[threadIdx.x >> 6] = sum_d2;
    }
    __syncthreads();
    if (threadIdx.x == 0) {
        float d1 = ((s1[0] + s1[1]) + (s1[2] + s1[3])) * (1.0f / 4096.0f);
        float d2 = ((s2[0] + s2[1]) + (s2[2] + s2[3])) * (1.0f / 4096.0f);
        out[0] = 0.5f * d2 + 0.5f * d1;  // loss
        out[1] = d1;                     // loss_D1
        out[2] = d2;                     // loss_D2
    }
}

extern "C" void kernel_launch(void* const* d_in, const int* in_sizes, int n_in,
                              void* d_out, int out_size, void* d_ws, size_t ws_size,
                              hipStream_t stream) {
    const float* rna    = (const float*)d_in[0];
    const float* wsi    = (const float*)d_in[1];
    const float* rnawsi = (const float*)d_in[2];
    const float* wsirna = (const float*)d_in[3];
    float* out = (float*)d_out;
    float* row_ss = (float*)d_ws;  // 16384 floats = 64 KB

    rowsumsq_kernel<<<2048, 256, 0, stream>>>(rna, wsi, rnawsi, wsirna, row_ss);
    finalize_kernel<<<1, 256, 0, stream>>>(row_ss, out);
}